// Round 9
// baseline (468.892 us; speedup 1.0000x reference)
//
#include <hip/hip_runtime.h>
#include <hip/hip_bf16.h>

#define N_TAG 128
#define T_LEN 512
#define START_TAG 126
#define STOP_TAG 127
#define PADJ 136  // bf16 elems per u-col row: 272B stride

typedef __attribute__((ext_vector_type(8))) __bf16 bf16x8;
typedef __attribute__((ext_vector_type(4))) float f32x4;

// Single-wave exp-space CRF DP. One 64-lane wave owns the ENTIRE 128x128
// matvec: A-frags for all 8 M-tiles of E=exp(trans) in 128 VGPRs, 32x
// mfma_f32_16x16x32_bf16 per step (8 independent 4-deep chains -> issue-
// bound). u-state roundtrips through LDS but within ONE wave: no barriers,
// no cross-wave skew (round 7/8's 1181cy/step was barrier+chain latency).
// LDS tag index XOR-swizzled by 16*(n&7): b128 reads 2-way bank alias (free).
// exps computed one step after load, two steps before use: off the chain.
// 2 real batches/wave (16 MFMA cols shadow them x8; loads coalesce).
__global__ __attribute__((amdgpu_flat_work_group_size(64, 64),
                          amdgpu_waves_per_eu(1, 1)))
void crf_wave_kernel(const float* __restrict__ feats,
                     const float* __restrict__ trans,
                     const int* __restrict__ tags,
                     float* __restrict__ out, int T) {
  const int lane = threadIdx.x;  // 0..63
  const int n = lane & 15;       // MFMA column (batch col, shadowed)
  const int g = lane >> 4;       // lane group
  const int bbase = blockIdx.x * 2;
  const int nb = n & 1;          // real batch within pair
  const int xr = (n & 7) << 4;   // LDS bank swizzle

  __shared__ __align__(16) __bf16 u_lds[2][16 * PADJ];

  // init u0 = one-hot(START), swizzled: u[c][k] at c*PADJ + (k ^ 16*(c&7))
  for (int idx = lane; idx < 16 * N_TAG; idx += 64) {
    int c = idx >> 7, k = idx & 127;
    u_lds[0][c * PADJ + (k ^ ((c & 7) << 4))] =
        (__bf16)((k == START_TAG) ? 1.0f : 0.0f);
  }

  // A-frags: A[mt][kk] lane holds E[16mt+n][32kk+8g+j], j=0..7
  bf16x8 A[8][4];
#pragma unroll
  for (int mt = 0; mt < 8; ++mt) {
#pragma unroll
    for (int kk = 0; kk < 4; ++kk) {
      const float* p = trans + (size_t)(16 * mt + n) * N_TAG + 32 * kk + 8 * g;
      f32x4 x = *(const f32x4*)p;
      f32x4 y = *(const f32x4*)(p + 4);
      bf16x8 v;
      v[0] = (__bf16)__expf(x[0]); v[1] = (__bf16)__expf(x[1]);
      v[2] = (__bf16)__expf(x[2]); v[3] = (__bf16)__expf(x[3]);
      v[4] = (__bf16)__expf(y[0]); v[5] = (__bf16)__expf(y[1]);
      v[6] = (__bf16)__expf(y[2]); v[7] = (__bf16)__expf(y[3]);
      A[mt][kk] = v;
    }
  }

  const float* fbase = feats + (size_t)(bbase + nb) * T * N_TAG + 4 * g;

  f32x4 upv[8];   // persists: last step's state feeds the epilogue
  float logZ = 0.0f;

#define LOADG(S_, T_)                                        \
  do {                                                       \
    const float* p_ = fbase + (size_t)(T_) * N_TAG;          \
    _Pragma("unroll")                                        \
    for (int m_ = 0; m_ < 8; ++m_)                           \
      S_[m_] = *(const f32x4*)(p_ + 16 * m_);                \
  } while (0)

#define EXPG(S_)                                             \
  do {                                                       \
    _Pragma("unroll")                                        \
    for (int m_ = 0; m_ < 8; ++m_) {                         \
      S_[m_][0] = __expf(S_[m_][0]);                         \
      S_[m_][1] = __expf(S_[m_][1]);                         \
      S_[m_][2] = __expf(S_[m_][2]);                         \
      S_[m_][3] = __expf(S_[m_][3]);                         \
    }                                                        \
  } while (0)

#define STEP(PAR_, S_, DOREN_)                                                \
  do {                                                                        \
    const __bf16* ub_ = u_lds[PAR_] + n * PADJ;                               \
    bf16x8 b_[4];                                                             \
    _Pragma("unroll")                                                         \
    for (int k_ = 0; k_ < 4; ++k_)                                            \
      b_[k_] = *(const bf16x8*)(ub_ + ((32 * k_ + 8 * g) ^ xr));              \
    f32x4 acc_[8];                                                            \
    _Pragma("unroll")                                                         \
    for (int m_ = 0; m_ < 8; ++m_) acc_[m_] = (f32x4){0.f, 0.f, 0.f, 0.f};    \
    _Pragma("unroll")                                                         \
    for (int k_ = 0; k_ < 4; ++k_) {                                          \
      _Pragma("unroll")                                                       \
      for (int m_ = 0; m_ < 8; ++m_)                                          \
        acc_[m_] = __builtin_amdgcn_mfma_f32_16x16x32_bf16(A[m_][k_], b_[k_], \
                                                           acc_[m_], 0, 0, 0);\
    }                                                                         \
    _Pragma("unroll")                                                         \
    for (int m_ = 0; m_ < 8; ++m_) {                                          \
      upv[m_][0] = acc_[m_][0] * S_[m_][0];                                   \
      upv[m_][1] = acc_[m_][1] * S_[m_][1];                                   \
      upv[m_][2] = acc_[m_][2] * S_[m_][2];                                   \
      upv[m_][3] = acc_[m_][3] * S_[m_][3];                                   \
    }                                                                         \
    if (DOREN_) {                                                             \
      float mx_ = upv[0][0];                                                  \
      _Pragma("unroll")                                                       \
      for (int m_ = 0; m_ < 8; ++m_)                                          \
        mx_ = fmaxf(mx_, fmaxf(fmaxf(upv[m_][0], upv[m_][1]),                 \
                               fmaxf(upv[m_][2], upv[m_][3])));               \
      mx_ = fmaxf(mx_, __shfl_xor(mx_, 16));                                  \
      mx_ = fmaxf(mx_, __shfl_xor(mx_, 32));                                  \
      float inv_ = 1.0f / mx_;                                                \
      _Pragma("unroll")                                                       \
      for (int m_ = 0; m_ < 8; ++m_) {                                        \
        upv[m_][0] *= inv_; upv[m_][1] *= inv_;                               \
        upv[m_][2] *= inv_; upv[m_][3] *= inv_;                               \
      }                                                                       \
      logZ += __logf(mx_);                                                    \
    }                                                                         \
    __bf16* ud_ = u_lds[(PAR_) ^ 1] + n * PADJ;                               \
    _Pragma("unroll")                                                         \
    for (int m_ = 0; m_ < 8; ++m_) {                                          \
      union { __bf16 h[2]; unsigned u; } lo_, hi_;                            \
      lo_.h[0] = (__bf16)upv[m_][0]; lo_.h[1] = (__bf16)upv[m_][1];           \
      hi_.h[0] = (__bf16)upv[m_][2]; hi_.h[1] = (__bf16)upv[m_][3];           \
      uint2 w_; w_.x = lo_.u; w_.y = hi_.u;                                   \
      *(uint2*)(ud_ + ((16 * m_ + 4 * g) ^ xr)) = w_;                         \
    }                                                                         \
  } while (0)

  f32x4 P[8], Q[8];
  LOADG(P, 0);
  LOADG(Q, 1);
  EXPG(P);  // prologue stall on first load: fine, once

  for (int t = 0; t < T; t += 2) {
    STEP(0, P, false);               // consume step t
    if (t + 2 < T) LOADG(P, t + 2);  // issue loads 2 steps ahead
    EXPG(Q);                         // Q landed ~1 step ago: exp off-chain
    STEP(1, Q, (t & 2) != 0);        // consume step t+1; renorm at t%4==3
    if (t + 3 < T) LOADG(Q, t + 3);
    EXPG(P);                         // P issued above, consumed next iter
  }

  // ---- forward score: log(sum_i u_i * exp(trans[STOP][i])) + logZ ----
  float term = 0.f;
#pragma unroll
  for (int m = 0; m < 8; ++m) {
    const float* ps = trans + (size_t)STOP_TAG * N_TAG + 16 * m + 4 * g;
    f32x4 ts = *(const f32x4*)ps;
    term += upv[m][0] * __expf(ts[0]) + upv[m][1] * __expf(ts[1]) +
            upv[m][2] * __expf(ts[2]) + upv[m][3] * __expf(ts[3]);
  }
  term += __shfl_xor(term, 16);
  term += __shfl_xor(term, 32);
  float fwd = __logf(term) + logZ;  // valid per-col in lanes g==0, n<2

  // ---- gold path score: lanes 0-31 batch 0, lanes 32-63 batch 1 ----
  const int half = lane >> 5, tl = lane & 31;
  const int* tg = tags + (size_t)(bbase + half) * T;
  const float* fg = feats + (size_t)(bbase + half) * T * N_TAG;
  float gsum = 0.f;
  for (int t = tl; t < T; t += 32) {
    int tag = tg[t];
    int prev = (t == 0) ? START_TAG : tg[t - 1];
    gsum += trans[(size_t)tag * N_TAG + prev] + fg[(size_t)t * N_TAG + tag];
    if (t == T - 1) gsum += trans[STOP_TAG * N_TAG + tag];
  }
#pragma unroll
  for (int s = 16; s; s >>= 1) gsum += __shfl_xor(gsum, s);  // within halves
  float gold0 = __shfl(gsum, 0);
  float gold1 = __shfl(gsum, 32);
  if (lane < 2) out[bbase + lane] = fwd - (lane ? gold1 : gold0);

#undef STEP
#undef EXPG
#undef LOADG
}

extern "C" void kernel_launch(void* const* d_in, const int* in_sizes, int n_in,
                              void* d_out, int out_size, void* d_ws, size_t ws_size,
                              hipStream_t stream) {
  const float* feats = (const float*)d_in[0];
  const float* trans = (const float*)d_in[1];
  const int* tags = (const int*)d_in[2];
  float* out = (float*)d_out;
  int B = in_sizes[0] / (T_LEN * N_TAG);  // 512
  crf_wave_kernel<<<B / 2, 64, 0, stream>>>(feats, trans, tags, out, T_LEN);
}

// Round 10
// 148.876 us; speedup vs baseline: 3.1495x; 3.1495x over previous
//
#include <hip/hip_runtime.h>
#include <hip/hip_bf16.h>

#define N_TAG 128
#define T_LEN 512
#define START_TAG 126
#define STOP_TAG 127

typedef __attribute__((ext_vector_type(8))) __bf16 bf16x8;
typedef __attribute__((ext_vector_type(4))) float f32x4;

// Split-direction exp-space CRF DP, zero-communication MFMA steps.
// score = log(s^T ∏ D_t E u0): forward wave computes u_255 (256 steps from
// one-hot START), backward wave computes w = (E^T D_256)...(E^T D_511) s
// (256 steps). Combine: log(w·u) + logZf + logZb - gold.
// Row-permutation tau(mt,ridx)=32(mt>>1)+8(ridx>>2)+4(mt&1)+(ridx&3) makes
// each lane's C-fragment exactly its next-step B-fragment (kk=mt>>1,
// j=4(mt&1)+r): no LDS, no barriers in the DP loop. Feats: 2 dword/lane ring
// (4-deep lookahead), 2 exps/lane, ds_bpermute redistribution (imm offsets).
__global__ __launch_bounds__(320, 1)
void crf_split_kernel(const float* __restrict__ feats,
                      const float* __restrict__ trans,
                      const int* __restrict__ tags,
                      float* __restrict__ out) {
  const int tid = threadIdx.x;
  const int wid = tid >> 6;
  const int lane = tid & 63;
  const int bbase = blockIdx.x * 2;

  __shared__ float Uf[2][N_TAG];
  __shared__ float Wb[2][N_TAG];
  __shared__ float LZ[4];
  __shared__ float GOLD[2];

  if (wid == 4) {
    // ---- gold wave: lanes 0-31 batch 0, lanes 32-63 batch 1 ----
    const int half = lane >> 5, tl = lane & 31;
    const int b = bbase + half;
    const int* tg = tags + (size_t)b * T_LEN;
    const float* fg = feats + (size_t)b * T_LEN * N_TAG;
    float gsum = 0.f;
    for (int t = tl; t < T_LEN; t += 32) {
      int tag = tg[t];
      int prev = (t == 0) ? START_TAG : tg[t - 1];
      gsum += trans[(size_t)tag * N_TAG + prev] + fg[(size_t)t * N_TAG + tag];
      if (t == T_LEN - 1) gsum += trans[STOP_TAG * N_TAG + tag];
    }
#pragma unroll
    for (int s = 16; s; s >>= 1) gsum += __shfl_xor(gsum, s);
    if (tl == 0) GOLD[half] = gsum;
    __syncthreads();
    // ---- combine ----
#pragma unroll
    for (int bL = 0; bL < 2; ++bL) {
      float sd = Uf[bL][lane] * Wb[bL][lane] +
                 Uf[bL][lane + 64] * Wb[bL][lane + 64];
#pragma unroll
      for (int s = 32; s; s >>= 1) sd += __shfl_xor(sd, s);
      if (lane == 0)
        out[bbase + bL] = __logf(sd) + LZ[2 * bL] + LZ[2 * bL + 1] - GOLD[bL];
    }
    return;
  }

  // ---- main DP waves: wid = 2*bL + dir (dir 0 fwd, 1 bwd) ----
  const int bL = wid >> 1, dir = wid & 1;
  const int batch = bbase + bL;
  const int n = lane & 15, g = lane >> 4;
  const float* fbase = feats + (size_t)batch * T_LEN * N_TAG;
  const int T0 = dir ? 510 : 0;
  const int TS = dir ? -1 : 1;
  const int ib = 32 * g;  // bpermute base byte address

  // ---- A fragments: tile mt holds E rows tau(mt, ridx); lane supplies
  //      row ridx=n, elements k = 32kk+8g+j. fwd: E[tau][k]; bwd: E[k][tau].
  bf16x8 A[8][4];
#pragma unroll
  for (int mt = 0; mt < 8; ++mt) {
    const int tau = 32 * (mt >> 1) + 8 * (n >> 2) + 4 * (mt & 1) + (n & 3);
#pragma unroll
    for (int kk = 0; kk < 4; ++kk) {
      bf16x8 v;
      if (dir == 0) {
        const float* p = trans + (size_t)tau * N_TAG + 32 * kk + 8 * g;
        f32x4 x = *(const f32x4*)p;
        f32x4 y = *(const f32x4*)(p + 4);
        v[0] = (__bf16)__expf(x[0]); v[1] = (__bf16)__expf(x[1]);
        v[2] = (__bf16)__expf(x[2]); v[3] = (__bf16)__expf(x[3]);
        v[4] = (__bf16)__expf(y[0]); v[5] = (__bf16)__expf(y[1]);
        v[6] = (__bf16)__expf(y[2]); v[7] = (__bf16)__expf(y[3]);
      } else {
#pragma unroll
        for (int j = 0; j < 8; ++j)
          v[j] = (__bf16)__expf(trans[(size_t)(32 * kk + 8 * g + j) * N_TAG + tau]);
      }
      A[mt][kk] = v;
    }
  }

  // ---- B init ----
  bf16x8 Bv[4];
#pragma unroll
  for (int kk = 0; kk < 4; ++kk) {
    bf16x8 z;
#pragma unroll
    for (int j = 0; j < 8; ++j) z[j] = (__bf16)0.0f;
    Bv[kk] = z;
  }
  if (dir == 0) {
    // u_{-1} = one-hot(START=126): tag 126 -> kk=3, g=3, j=6
    if (g == 3) Bv[3][6] = (__bf16)1.0f;
  } else {
    // b0 = ef_511 ⊙ s, s_j = exp(trans[STOP][j]); tag = 32kk+8g+j
    const float* s127 = trans + (size_t)STOP_TAG * N_TAG;
    const float* f511 = fbase + (size_t)(T_LEN - 1) * N_TAG;
#pragma unroll
    for (int kk = 0; kk < 4; ++kk) {
      const int off = 32 * kk + 8 * g;
      f32x4 s0 = *(const f32x4*)(s127 + off);
      f32x4 s1 = *(const f32x4*)(s127 + off + 4);
      f32x4 e0 = *(const f32x4*)(f511 + off);
      f32x4 e1 = *(const f32x4*)(f511 + off + 4);
      bf16x8 v;
      v[0] = (__bf16)__expf(s0[0] + e0[0]); v[1] = (__bf16)__expf(s0[1] + e0[1]);
      v[2] = (__bf16)__expf(s0[2] + e0[2]); v[3] = (__bf16)__expf(s0[3] + e0[3]);
      v[4] = (__bf16)__expf(s1[0] + e1[0]); v[5] = (__bf16)__expf(s1[1] + e1[1]);
      v[6] = (__bf16)__expf(s1[2] + e1[2]); v[7] = (__bf16)__expf(s1[3] + e1[3]);
      Bv[kk] = v;
    }
  }

  // ---- feat ring: slot s holds row t_cur (t==s mod 4); 2 dwords/lane ----
  float Lr[4][2];
#pragma unroll
  for (int s = 0; s < 4; ++s) {
    const float* rp = fbase + (size_t)(T0 + TS * s) * N_TAG;
    Lr[s][0] = rp[lane];
    Lr[s][1] = rp[lane + 64];
  }
  Lr[0][0] = __expf(Lr[0][0]);
  Lr[0][1] = __expf(Lr[0][1]);
  float logZ = 0.0f;

  // EF[mt][r] = ef[tau(mt,4g+r)]; tau = 32a+8g+4bb+r (a=mt>>1, bb=mt&1):
  // a<2 -> reg0 lane tau; a>=2 -> reg1 lane tau-64. Imm-offset bpermutes.
#define BPERM(DST, SLOT)                                                     \
  {                                                                          \
    _Pragma("unroll") for (int a = 0; a < 4; ++a) {                          \
      int sv_ = __float_as_int((a < 2) ? Lr[SLOT][0] : Lr[SLOT][1]);         \
      _Pragma("unroll") for (int bb = 0; bb < 2; ++bb) {                     \
        _Pragma("unroll") for (int r = 0; r < 4; ++r) {                      \
          int w_ = __builtin_amdgcn_ds_bpermute(                             \
              ib + 128 * (a & 1) + 16 * bb + 4 * r, sv_);                    \
          DST[2 * a + bb][r] = __int_as_float(w_);                           \
        }                                                                    \
      }                                                                      \
    }                                                                        \
  }

#define RENORM(ACC)                                                          \
  {                                                                          \
    float mx_ = ACC[0][0];                                                   \
    _Pragma("unroll") for (int mt = 0; mt < 8; ++mt)                         \
        mx_ = fmaxf(mx_, fmaxf(fmaxf(ACC[mt][0], ACC[mt][1]),                \
                               fmaxf(ACC[mt][2], ACC[mt][3])));              \
    mx_ = fmaxf(mx_, __shfl_xor(mx_, 16));                                   \
    mx_ = fmaxf(mx_, __shfl_xor(mx_, 32));                                   \
    int eb_ = __float_as_int(mx_) & 0x7f800000;                              \
    float inv_ = __int_as_float(0x7f000000 - eb_); /* exact 2^-a */          \
    logZ += (float)((eb_ >> 23) - 127) * 0.69314718056f;                     \
    _Pragma("unroll") for (int mt = 0; mt < 8; ++mt) {                       \
      ACC[mt][0] *= inv_; ACC[mt][1] *= inv_;                                \
      ACC[mt][2] *= inv_; ACC[mt][3] *= inv_;                                \
    }                                                                        \
  }

#define ITER(S, SX, KP4, DOREN)                                              \
  {                                                                          \
    f32x4 EF[8];                                                             \
    BPERM(EF, S);                                                            \
    f32x4 acc[8];                                                            \
    _Pragma("unroll") for (int mt = 0; mt < 8; ++mt)                         \
        acc[mt] = (f32x4){0.f, 0.f, 0.f, 0.f};                               \
    _Pragma("unroll") for (int kk = 0; kk < 4; ++kk) {                       \
      _Pragma("unroll") for (int mt = 0; mt < 8; ++mt)                       \
          acc[mt] = __builtin_amdgcn_mfma_f32_16x16x32_bf16(                 \
              A[mt][kk], Bv[kk], acc[mt], 0, 0, 0);                          \
    }                                                                        \
    _Pragma("unroll") for (int mt = 0; mt < 8; ++mt) {                       \
      acc[mt][0] *= EF[mt][0]; acc[mt][1] *= EF[mt][1];                      \
      acc[mt][2] *= EF[mt][2]; acc[mt][3] *= EF[mt][3];                      \
    }                                                                        \
    if (DOREN) RENORM(acc);                                                  \
    _Pragma("unroll") for (int kk = 0; kk < 4; ++kk) {                       \
      bf16x8 nb;                                                             \
      nb[0] = (__bf16)acc[2 * kk][0];     nb[1] = (__bf16)acc[2 * kk][1];    \
      nb[2] = (__bf16)acc[2 * kk][2];     nb[3] = (__bf16)acc[2 * kk][3];    \
      nb[4] = (__bf16)acc[2 * kk + 1][0]; nb[5] = (__bf16)acc[2 * kk + 1][1];\
      nb[6] = (__bf16)acc[2 * kk + 1][2]; nb[7] = (__bf16)acc[2 * kk + 1][3];\
      Bv[kk] = nb;                                                           \
    }                                                                        \
    Lr[SX][0] = __expf(Lr[SX][0]); /* next step's ef (landed 3 iters ago) */ \
    Lr[SX][1] = __expf(Lr[SX][1]);                                           \
    {                                                                        \
      const float* rp_ = fbase + (size_t)(T0 + TS * (KP4)) * N_TAG;          \
      Lr[S][0] = rp_[lane]; /* refill slot: 4-iter lookahead */              \
      Lr[S][1] = rp_[lane + 64];                                             \
    }                                                                        \
  }

  // ---- 255 full steps + tail: 256 MFMA steps total ----
  for (int kb = 0; kb < 63; ++kb) {
    const int k0 = kb * 4;
    ITER(0, 1, k0 + 4, false);
    ITER(1, 2, k0 + 5, false);
    ITER(2, 3, k0 + 6, false);
    ITER(3, 0, k0 + 7, true);
  }
  ITER(0, 1, 256, false);  // k=252
  ITER(1, 2, 257, false);  // k=253
  ITER(2, 3, 258, false);  // k=254

  // ---- tail (k=255): fwd multiplies ef_255; bwd keeps raw E^T·b ----
  f32x4 upF[8];
  {
    f32x4 EF[8];
    BPERM(EF, 3);
    f32x4 acc[8];
#pragma unroll
    for (int mt = 0; mt < 8; ++mt) acc[mt] = (f32x4){0.f, 0.f, 0.f, 0.f};
#pragma unroll
    for (int kk = 0; kk < 4; ++kk) {
#pragma unroll
      for (int mt = 0; mt < 8; ++mt)
        acc[mt] = __builtin_amdgcn_mfma_f32_16x16x32_bf16(A[mt][kk], Bv[kk],
                                                          acc[mt], 0, 0, 0);
    }
    if (dir == 0) {
#pragma unroll
      for (int mt = 0; mt < 8; ++mt) {
        acc[mt][0] *= EF[mt][0]; acc[mt][1] *= EF[mt][1];
        acc[mt][2] *= EF[mt][2]; acc[mt][3] *= EF[mt][3];
      }
    }
    RENORM(acc);  // final normalization so the dot can't overflow f32
#pragma unroll
    for (int mt = 0; mt < 8; ++mt) upF[mt] = acc[mt];
  }

  // ---- publish final vectors (plain tag order) ----
  float* dst = (dir == 0) ? Uf[bL] : Wb[bL];
  if (n == 0) {
#pragma unroll
    for (int mt = 0; mt < 8; ++mt) {
      const int base = 32 * (mt >> 1) + 8 * g + 4 * (mt & 1);
#pragma unroll
      for (int r = 0; r < 4; ++r) dst[base + r] = upF[mt][r];
    }
  }
  if (lane == 0) LZ[wid] = logZ;
  __syncthreads();
#undef ITER
#undef RENORM
#undef BPERM
}

extern "C" void kernel_launch(void* const* d_in, const int* in_sizes, int n_in,
                              void* d_out, int out_size, void* d_ws, size_t ws_size,
                              hipStream_t stream) {
  const float* feats = (const float*)d_in[0];
  const float* trans = (const float*)d_in[1];
  const int* tags = (const int*)d_in[2];
  float* out = (float*)d_out;
  int B = in_sizes[0] / (T_LEN * N_TAG);  // 512
  crf_split_kernel<<<B / 2, 320, 0, stream>>>(feats, trans, tags, out);
}